// Round 1
// baseline (157.751 us; speedup 1.0000x reference)
//
#include <hip/hip_runtime.h>
#include <cfloat>

typedef unsigned short u16;
typedef u16   u16x4 __attribute__((ext_vector_type(4)));
typedef float f32x4 __attribute__((ext_vector_type(4)));
typedef _Float16 f16x8 __attribute__((ext_vector_type(8)));

#define GL2LDS(gp, lp) __builtin_amdgcn_global_load_lds(                      \
    (const __attribute__((address_space(1))) void*)(gp),                      \
    (__attribute__((address_space(3))) void*)(lp), 16, 0, 0)

__device__ __forceinline__ void f32_to_f16pair(float f, u16& hi, u16& lo) {
  _Float16 h = (_Float16)f;            // RNE
  _Float16 l = (_Float16)(f - (float)h);  // residual (exact subtraction)
  hi = __builtin_bit_cast(u16, h);
  lo = __builtin_bit_cast(u16, l);
}

// Pretile a [R,512] fp32 matrix into f16 hi/lo panels of 128 rows x 64 cols,
// XOR-swizzled ( byte ^= (row&7)<<4 ), stored as the exact LDS image so
// global_load_lds can copy panels linearly. Optionally emit row sum-of-squares
// and a plain fp32 copy (codebook passthrough output).
__global__ __launch_bounds__(128) void vq_prep(
    const float* __restrict__ src, u16* __restrict__ hi_p, u16* __restrict__ lo_p,
    float* __restrict__ sq, float* __restrict__ copy_out) {
  __shared__ float red[2];
  const int row_g = blockIdx.x;          // global row
  const int t = threadIdx.x;             // 0..127, 4 floats each
  float4 v = reinterpret_cast<const float4*>(src + (size_t)row_g * 512)[t];
  if (copy_out)
    reinterpret_cast<float4*>(copy_out + (size_t)row_g * 512)[t] = v;
  u16 hi[4], lo[4];
  float f[4] = {v.x, v.y, v.z, v.w};
  #pragma unroll
  for (int i = 0; i < 4; ++i) f32_to_f16pair(f[i], hi[i], lo[i]);
  const int d = t * 4;
  const int tile = row_g >> 7, r = row_g & 127;
  const int dstep = d >> 6, c = d & 63;
  const size_t pbase = ((size_t)tile * 8 + dstep) * 16384;   // bytes per panel
  const unsigned boff = ((unsigned)(r * 128 + c * 2)) ^ ((unsigned)(r & 7) << 4);
  u16x4 th = {hi[0], hi[1], hi[2], hi[3]};
  u16x4 tl = {lo[0], lo[1], lo[2], lo[3]};
  *reinterpret_cast<u16x4*>((char*)hi_p + pbase + boff) = th;
  *reinterpret_cast<u16x4*>((char*)lo_p + pbase + boff) = tl;
  if (sq) {
    float s = v.x*v.x + v.y*v.y + v.z*v.z + v.w*v.w;
    #pragma unroll
    for (int m = 1; m < 64; m <<= 1) s += __shfl_xor(s, m);
    if ((t & 63) == 0) red[t >> 6] = s;
    __syncthreads();
    if (t == 0) sq[row_g] = red[0] + red[1];
  }
}

// Distance GEMM + per-tile argmin.  Tile 128x128, BK=64, 4 waves (2x2),
// mfma_f32_16x16x32_f16 with hi/lo split (3 MFMAs per fragment pair).
// score = c2[col] - 2*dot  (x2 row-constant, dropped for argmin).
template <int INLINE_A>
__global__ __launch_bounds__(256) void vq_gemm(
    const float* __restrict__ X,
    const u16* __restrict__ Ahi, const u16* __restrict__ Alo,
    const u16* __restrict__ Bhi, const u16* __restrict__ Blo,
    const float* __restrict__ c2,
    float2* __restrict__ part, int nsub_stride) {
  __shared__ u16 sAhi[128 * 64], sAlo[128 * 64], sBhi[128 * 64], sBlo[128 * 64];
  const int tid = threadIdx.x;
  const int lane = tid & 63, wid = tid >> 6;
  const int wm = wid >> 1, wn = wid & 1;
  const int mtile = blockIdx.x, ntile = blockIdx.y;
  const int lrow = lane & 15, kgrp = lane >> 4;
  f32x4 acc[4][4] = {};

  for (int ds = 0; ds < 8; ++ds) {
    // ---- stage B (codes) via global_load_lds from pre-swizzled panels
    {
      const size_t pb = ((size_t)ntile * 8 + ds) * 16384;
      const char* gh = (const char*)Bhi + pb;
      const char* gl = (const char*)Blo + pb;
      #pragma unroll
      for (int ch = 0; ch < 4; ++ch) {
        const int off = (wid * 4 + ch) * 1024;
        GL2LDS(gh + off + lane * 16, (char*)sBhi + off);
        GL2LDS(gl + off + lane * 16, (char*)sBlo + off);
      }
    }
    // ---- stage A (tokens)
    if constexpr (INLINE_A) {
      const float* ga = X + ((size_t)mtile * 128) * 512 + ds * 64;
      const int r0 = tid >> 4, c0 = (tid & 15) * 4;
      #pragma unroll
      for (int p = 0; p < 8; ++p) {
        const int r = r0 + p * 16;
        float4 v = *reinterpret_cast<const float4*>(ga + (size_t)r * 512 + c0);
        u16 hi[4], lo[4];
        float f[4] = {v.x, v.y, v.z, v.w};
        #pragma unroll
        for (int i = 0; i < 4; ++i) f32_to_f16pair(f[i], hi[i], lo[i]);
        const unsigned boff = ((unsigned)(r * 128 + c0 * 2)) ^ ((unsigned)(r & 7) << 4);
        u16x4 th = {hi[0], hi[1], hi[2], hi[3]};
        u16x4 tl = {lo[0], lo[1], lo[2], lo[3]};
        *reinterpret_cast<u16x4*>((char*)sAhi + boff) = th;
        *reinterpret_cast<u16x4*>((char*)sAlo + boff) = tl;
      }
    } else {
      const size_t pa = ((size_t)mtile * 8 + ds) * 16384;
      const char* gh = (const char*)Ahi + pa;
      const char* gl = (const char*)Alo + pa;
      #pragma unroll
      for (int ch = 0; ch < 4; ++ch) {
        const int off = (wid * 4 + ch) * 1024;
        GL2LDS(gh + off + lane * 16, (char*)sAhi + off);
        GL2LDS(gl + off + lane * 16, (char*)sAlo + off);
      }
    }
    __syncthreads();
    // ---- compute
    #pragma unroll
    for (int ks = 0; ks < 2; ++ks) {
      f16x8 ahi[4], alo[4], bhi[4], blo[4];
      const int kbyte = ks * 64 + kgrp * 16;
      #pragma unroll
      for (int fr = 0; fr < 4; ++fr) {
        const int ar = wm * 64 + fr * 16 + lrow;
        const unsigned ao = ((unsigned)(ar * 128 + kbyte)) ^ ((unsigned)(ar & 7) << 4);
        ahi[fr] = *reinterpret_cast<const f16x8*>((const char*)sAhi + ao);
        alo[fr] = *reinterpret_cast<const f16x8*>((const char*)sAlo + ao);
        const int br = wn * 64 + fr * 16 + lrow;
        const unsigned bo = ((unsigned)(br * 128 + kbyte)) ^ ((unsigned)(br & 7) << 4);
        bhi[fr] = *reinterpret_cast<const f16x8*>((const char*)sBhi + bo);
        blo[fr] = *reinterpret_cast<const f16x8*>((const char*)sBlo + bo);
      }
      #pragma unroll
      for (int i = 0; i < 4; ++i)
        #pragma unroll
        for (int j = 0; j < 4; ++j) {
          acc[i][j] = __builtin_amdgcn_mfma_f32_16x16x32_f16(ahi[i], bhi[j], acc[i][j], 0, 0, 0);
          acc[i][j] = __builtin_amdgcn_mfma_f32_16x16x32_f16(ahi[i], blo[j], acc[i][j], 0, 0, 0);
          acc[i][j] = __builtin_amdgcn_mfma_f32_16x16x32_f16(alo[i], bhi[j], acc[i][j], 0, 0, 0);
        }
    }
    __syncthreads();
  }
  // ---- epilogue: per-row argmin over this wave's 64 cols, tie-break low idx
  float c2v[4];
  #pragma unroll
  for (int j = 0; j < 4; ++j) c2v[j] = c2[ntile * 128 + wn * 64 + j * 16 + lrow];
  #pragma unroll
  for (int i = 0; i < 4; ++i) {
    #pragma unroll
    for (int jj = 0; jj < 4; ++jj) {
      float v = FLT_MAX; int idx = 0x7fffffff;
      #pragma unroll
      for (int j = 0; j < 4; ++j) {
        const float sc = c2v[j] - 2.0f * acc[i][j][jj];
        const int col = ntile * 128 + wn * 64 + j * 16 + lrow;
        if (sc < v || (sc == v && col < idx)) { v = sc; idx = col; }
      }
      #pragma unroll
      for (int m = 1; m < 16; m <<= 1) {
        const float ov = __shfl_xor(v, m);
        const int oi = __shfl_xor(idx, m);
        if (ov < v || (ov == v && oi < idx)) { v = ov; idx = oi; }
      }
      if (lrow == 0) {
        const int row = mtile * 128 + wm * 64 + i * 16 + kgrp * 4 + jj;
        part[(size_t)row * nsub_stride + (ntile * 2 + wn)] =
            make_float2(v, __int_as_float(idx));
      }
    }
  }
}

// Final: reduce nsub partials per row, gather codebook row, write outputs.
__global__ __launch_bounds__(256) void vq_final(
    const float* __restrict__ X, const float* __restrict__ CB,
    const float2* __restrict__ part,
    float* __restrict__ out0, float* __restrict__ out1, float* __restrict__ out2,
    int nsub) {
  const int row = blockIdx.x * 4 + (threadIdx.x >> 6);
  const int l = threadIdx.x & 63;
  float v = FLT_MAX; int idx = 0x7fffffff;
  for (int i = l; i < nsub; i += 64) {
    const float2 p = part[(size_t)row * nsub + i];
    const int pi = __float_as_int(p.y);
    if (p.x < v || (p.x == v && pi < idx)) { v = p.x; idx = pi; }
  }
  #pragma unroll
  for (int m = 1; m < 64; m <<= 1) {
    const float ov = __shfl_xor(v, m);
    const int oi = __shfl_xor(idx, m);
    if (ov < v || (ov == v && oi < idx)) { v = ov; idx = oi; }
  }
  const float4* xr = reinterpret_cast<const float4*>(X + (size_t)row * 512);
  const float4* cr = reinterpret_cast<const float4*>(CB + (size_t)idx * 512);
  float4* q  = reinterpret_cast<float4*>(out0 + (size_t)row * 512);
  float4* ls = reinterpret_cast<float4*>(out1 + (size_t)row * 512);
  #pragma unroll
  for (int p = 0; p < 2; ++p) {
    const int e = l + 64 * p;
    const float4 xv = xr[e], cv = cr[e];
    float4 d4, qv, lv;
    d4.x = cv.x - xv.x; d4.y = cv.y - xv.y; d4.z = cv.z - xv.z; d4.w = cv.w - xv.w;
    qv.x = xv.x + d4.x; qv.y = xv.y + d4.y; qv.z = xv.z + d4.z; qv.w = xv.w + d4.w;
    lv.x = d4.x * d4.x; lv.y = d4.y * d4.y; lv.z = d4.z * d4.z; lv.w = d4.w * d4.w;
    q[e] = qv; ls[e] = lv;
  }
  if (l == 0) out2[row] = (float)idx;
}

extern "C" void kernel_launch(void* const* d_in, const int* in_sizes, int n_in,
                              void* d_out, int out_size, void* d_ws, size_t ws_size,
                              hipStream_t stream) {
  const float* X  = (const float*)d_in[0];   // [M,512] fp32
  const float* CB = (const float*)d_in[1];   // [K,512] fp32
  const int D = 512;
  const int M = in_sizes[0] / D;             // 16384
  const int K = in_sizes[1] / D;             // 2048
  float* out0 = (float*)d_out;               // quantized_ste [M,512]
  float* out1 = out0 + (size_t)M * D;        // loss          [M,512]
  float* out2 = out1 + (size_t)M * D;        // nn_idx (as f32) [M]
  float* out3 = out2 + M;                    // codebook copy [K,512]

  char* ws = (char*)d_ws;
  size_t off = 0;
  u16* Bhi = (u16*)(ws + off); off += (size_t)K * D * 2;
  u16* Blo = (u16*)(ws + off); off += (size_t)K * D * 2;
  float* c2 = (float*)(ws + off); off += (size_t)K * 4;
  const int nsub = K / 64;
  float2* part = (float2*)(ws + off); off += (size_t)M * nsub * 8;
  u16* Ahi = (u16*)(ws + off);
  u16* Alo = (u16*)(ws + off + (size_t)M * D * 2);
  const size_t need_big = off + (size_t)M * D * 4;
  const bool big = (ws_size >= need_big);

  vq_prep<<<K, 128, 0, stream>>>(CB, Bhi, Blo, c2, out3);
  dim3 g(M / 128, K / 128);
  if (big) {
    vq_prep<<<M, 128, 0, stream>>>(X, Ahi, Alo, nullptr, nullptr);
    vq_gemm<0><<<g, 256, 0, stream>>>(X, Ahi, Alo, Bhi, Blo, c2, part, nsub);
  } else {
    vq_gemm<1><<<g, 256, 0, stream>>>(X, nullptr, nullptr, Bhi, Blo, c2, part, nsub);
  }
  vq_final<<<M / 4, 256, 0, stream>>>(X, CB, part, out0, out1, out2, nsub);
}

// Round 2
// 151.544 us; speedup vs baseline: 1.0410x; 1.0410x over previous
//
#include <hip/hip_runtime.h>
#include <cfloat>

typedef unsigned short u16;
typedef u16   u16x4 __attribute__((ext_vector_type(4)));
typedef float f32x4 __attribute__((ext_vector_type(4)));
typedef _Float16 f16x8 __attribute__((ext_vector_type(8)));

#define GL2LDS(gp, lp) __builtin_amdgcn_global_load_lds(                      \
    (const __attribute__((address_space(1))) void*)(gp),                      \
    (__attribute__((address_space(3))) void*)(lp), 16, 0, 0)

__device__ __forceinline__ void f32_to_f16pair(float f, u16& hi, u16& lo) {
  _Float16 h = (_Float16)f;               // RNE
  _Float16 l = (_Float16)(f - (float)h);  // residual (exact subtraction)
  hi = __builtin_bit_cast(u16, h);
  lo = __builtin_bit_cast(u16, l);
}

// Pretile a [R,512] fp32 matrix into f16 hi/lo panels.
// Panel unit: (tile of 256 rows, K-step s of 32 cols) = 32768 bytes.
// Row layout inside a unit: 128 B = [hi: 32 f16 | lo: 32 f16], byte offset
// XOR-swizzled with ((r&7)<<4) — stored as the exact LDS image so
// global_load_lds can copy units linearly (swizzle both-sides, rule #21).
// Optionally emits row sum-of-squares and a plain fp32 passthrough copy.
__global__ __launch_bounds__(128) void vq_prep(
    const float* __restrict__ src, u16* __restrict__ pan,
    float* __restrict__ sq, float* __restrict__ copy_out) {
  __shared__ float red[2];
  const int row_g = blockIdx.x;
  const int t = threadIdx.x;             // 0..127, 4 floats each
  float4 v = reinterpret_cast<const float4*>(src + (size_t)row_g * 512)[t];
  if (copy_out)
    reinterpret_cast<float4*>(copy_out + (size_t)row_g * 512)[t] = v;
  u16 hi[4], lo[4];
  float f[4] = {v.x, v.y, v.z, v.w};
  #pragma unroll
  for (int i = 0; i < 4; ++i) f32_to_f16pair(f[i], hi[i], lo[i]);
  const int d = t * 4;
  const int tile = row_g >> 8, r = row_g & 255;
  const int s = d >> 5, c = d & 31;
  const size_t pbase = ((size_t)tile * 16 + s) * 32768;
  const unsigned swz = ((unsigned)(r & 7)) << 4;
  const unsigned bh = ((unsigned)(r * 128 + c * 2)) ^ swz;
  const unsigned bl = ((unsigned)(r * 128 + 64 + c * 2)) ^ swz;
  u16x4 th = {hi[0], hi[1], hi[2], hi[3]};
  u16x4 tl = {lo[0], lo[1], lo[2], lo[3]};
  *reinterpret_cast<u16x4*>((char*)pan + pbase + bh) = th;
  *reinterpret_cast<u16x4*>((char*)pan + pbase + bl) = tl;
  if (sq) {
    float ssum = v.x*v.x + v.y*v.y + v.z*v.z + v.w*v.w;
    #pragma unroll
    for (int m = 1; m < 64; m <<= 1) ssum += __shfl_xor(ssum, m);
    if ((t & 63) == 0) red[t >> 6] = ssum;
    __syncthreads();
    if (t == 0) sq[row_g] = red[0] + red[1];
  }
}

// Distance GEMM + per-tile argmin. Tile 256x256, BK=32, 8 waves (2x4),
// per-wave output 128x64. mfma_f32_16x16x32_f16, hi/lo split (3 MFMAs).
// Double-buffered LDS (128 KiB), T3 minimum-2-phase: stage(s+1) issued
// before compute(s); __syncthreads' vmcnt drain lands after the compute.
// score = c2[col] - 2*dot (x2 row-constant, dropped for argmin).
template <int INLINE_A>
__global__ __launch_bounds__(512, 2) void vq_gemm(
    const float* __restrict__ X,
    const u16* __restrict__ Apan, const u16* __restrict__ Bpan,
    const float* __restrict__ c2,
    float2* __restrict__ part, int nmt) {
  __shared__ u16 sA[2][16384], sB[2][16384];   // 2 x 32 KiB each
  const int tid = threadIdx.x;
  const int lane = tid & 63, wid = tid >> 6;   // 8 waves
  const int wm = wid >> 2, wn = wid & 3;       // 2 x 4
  // bijective XCD swizzle (nwg % 8 == 0)
  const int nwg = gridDim.x;
  const int bid = blockIdx.x;
  const int swb = (bid & 7) * (nwg >> 3) + (bid >> 3);
  const int mtile = swb % nmt, ntile = swb / nmt;
  const int lrow = lane & 15, kgrp = lane >> 4;
  f32x4 acc[8][4] = {};

  auto stage = [&](int s, int buf) {
    // B unit
    const char* gb = (const char*)Bpan + ((size_t)ntile * 16 + s) * 32768;
    #pragma unroll
    for (int ch = 0; ch < 4; ++ch) {
      const int off = (wid * 4 + ch) * 1024;
      GL2LDS(gb + off + lane * 16, (char*)sB[buf] + off);
    }
    if constexpr (!INLINE_A) {
      const char* ga = (const char*)Apan + ((size_t)mtile * 16 + s) * 32768;
      #pragma unroll
      for (int ch = 0; ch < 4; ++ch) {
        const int off = (wid * 4 + ch) * 1024;
        GL2LDS(ga + off + lane * 16, (char*)sA[buf] + off);
      }
    } else {
      // inline convert A tile (fallback when ws can't hold A panels)
      const float* ga = X + ((size_t)mtile * 256) * 512 + s * 32;
      #pragma unroll
      for (int p = 0; p < 4; ++p) {
        const int cch = tid + p * 512;           // 2048 float4 chunks
        const int r = cch >> 3, c0 = (cch & 7) * 4;
        float4 v = *reinterpret_cast<const float4*>(ga + (size_t)r * 512 + c0);
        u16 hi[4], lo[4];
        float f[4] = {v.x, v.y, v.z, v.w};
        #pragma unroll
        for (int i2 = 0; i2 < 4; ++i2) f32_to_f16pair(f[i2], hi[i2], lo[i2]);
        const unsigned swz = ((unsigned)(r & 7)) << 4;
        const unsigned bh = ((unsigned)(r * 128 + c0 * 2)) ^ swz;
        const unsigned bl = ((unsigned)(r * 128 + 64 + c0 * 2)) ^ swz;
        u16x4 th = {hi[0], hi[1], hi[2], hi[3]};
        u16x4 tl = {lo[0], lo[1], lo[2], lo[3]};
        *reinterpret_cast<u16x4*>((char*)sA[buf] + bh) = th;
        *reinterpret_cast<u16x4*>((char*)sA[buf] + bl) = tl;
      }
    }
  };

  stage(0, 0);
  __syncthreads();
  int cur = 0;
  for (int s = 0; s < 16; ++s) {
    if (s + 1 < 16) stage(s + 1, cur ^ 1);
    // ---- compute from buf[cur]
    f16x8 bhi[4], blo[4];
    #pragma unroll
    for (int j = 0; j < 4; ++j) {
      const int br = wn * 64 + j * 16 + lrow;
      const unsigned swz = ((unsigned)(br & 7)) << 4;
      const unsigned b0 = (unsigned)(br * 128 + kgrp * 16);
      bhi[j] = *reinterpret_cast<const f16x8*>((const char*)sB[cur] + (b0 ^ swz));
      blo[j] = *reinterpret_cast<const f16x8*>((const char*)sB[cur] + ((b0 + 64) ^ swz));
    }
    #pragma unroll
    for (int i = 0; i < 8; ++i) {
      const int ar = wm * 128 + i * 16 + lrow;
      const unsigned swz = ((unsigned)(ar & 7)) << 4;
      const unsigned a0 = (unsigned)(ar * 128 + kgrp * 16);
      f16x8 ahi = *reinterpret_cast<const f16x8*>((const char*)sA[cur] + (a0 ^ swz));
      f16x8 alo = *reinterpret_cast<const f16x8*>((const char*)sA[cur] + ((a0 + 64) ^ swz));
      #pragma unroll
      for (int j = 0; j < 4; ++j) {
        acc[i][j] = __builtin_amdgcn_mfma_f32_16x16x32_f16(ahi, bhi[j], acc[i][j], 0, 0, 0);
        acc[i][j] = __builtin_amdgcn_mfma_f32_16x16x32_f16(ahi, blo[j], acc[i][j], 0, 0, 0);
        acc[i][j] = __builtin_amdgcn_mfma_f32_16x16x32_f16(alo, bhi[j], acc[i][j], 0, 0, 0);
      }
    }
    __syncthreads();
    cur ^= 1;
  }

  // ---- epilogue: per-row argmin over this wave's 64 cols, tie-break low idx
  float c2v[4];
  #pragma unroll
  for (int j = 0; j < 4; ++j) c2v[j] = c2[ntile * 256 + wn * 64 + j * 16 + lrow];
  #pragma unroll
  for (int i = 0; i < 8; ++i) {
    #pragma unroll
    for (int jj = 0; jj < 4; ++jj) {
      float v = FLT_MAX; int idx = 0x7fffffff;
      #pragma unroll
      for (int j = 0; j < 4; ++j) {
        const float sc = c2v[j] - 2.0f * acc[i][j][jj];
        const int col = ntile * 256 + wn * 64 + j * 16 + lrow;
        if (sc < v || (sc == v && col < idx)) { v = sc; idx = col; }
      }
      #pragma unroll
      for (int m = 1; m < 16; m <<= 1) {
        const float ov = __shfl_xor(v, m);
        const int oi = __shfl_xor(idx, m);
        if (ov < v || (ov == v && oi < idx)) { v = ov; idx = oi; }
      }
      if (lrow == 0) {
        const int row = mtile * 256 + wm * 128 + i * 16 + kgrp * 4 + jj;
        part[(size_t)row * 32 + (ntile * 4 + wn)] =
            make_float2(v, __int_as_float(idx));
      }
    }
  }
}

// Final: reduce 32 partials per row, gather codebook row, write outputs.
__global__ __launch_bounds__(256) void vq_final(
    const float* __restrict__ X, const float* __restrict__ CB,
    const float2* __restrict__ part,
    float* __restrict__ out0, float* __restrict__ out1, float* __restrict__ out2,
    int nsub) {
  const int row = blockIdx.x * 4 + (threadIdx.x >> 6);
  const int l = threadIdx.x & 63;
  float v = FLT_MAX; int idx = 0x7fffffff;
  for (int i = l; i < nsub; i += 64) {
    const float2 p = part[(size_t)row * nsub + i];
    const int pi = __float_as_int(p.y);
    if (p.x < v || (p.x == v && pi < idx)) { v = p.x; idx = pi; }
  }
  #pragma unroll
  for (int m = 1; m < 64; m <<= 1) {
    const float ov = __shfl_xor(v, m);
    const int oi = __shfl_xor(idx, m);
    if (ov < v || (ov == v && oi < idx)) { v = ov; idx = oi; }
  }
  const float4* xr = reinterpret_cast<const float4*>(X + (size_t)row * 512);
  const float4* cr = reinterpret_cast<const float4*>(CB + (size_t)idx * 512);
  float4* q  = reinterpret_cast<float4*>(out0 + (size_t)row * 512);
  float4* ls = reinterpret_cast<float4*>(out1 + (size_t)row * 512);
  #pragma unroll
  for (int p = 0; p < 2; ++p) {
    const int e = l + 64 * p;
    const float4 xv = xr[e], cv = cr[e];
    float4 d4, qv, lv;
    d4.x = cv.x - xv.x; d4.y = cv.y - xv.y; d4.z = cv.z - xv.z; d4.w = cv.w - xv.w;
    qv.x = xv.x + d4.x; qv.y = xv.y + d4.y; qv.z = xv.z + d4.z; qv.w = xv.w + d4.w;
    lv.x = d4.x * d4.x; lv.y = d4.y * d4.y; lv.z = d4.z * d4.z; lv.w = d4.w * d4.w;
    q[e] = qv; ls[e] = lv;
  }
  if (l == 0) out2[row] = (float)idx;
}

extern "C" void kernel_launch(void* const* d_in, const int* in_sizes, int n_in,
                              void* d_out, int out_size, void* d_ws, size_t ws_size,
                              hipStream_t stream) {
  const float* X  = (const float*)d_in[0];   // [M,512] fp32
  const float* CB = (const float*)d_in[1];   // [K,512] fp32
  const int D = 512;
  const int M = in_sizes[0] / D;             // 16384
  const int K = in_sizes[1] / D;             // 2048
  float* out0 = (float*)d_out;               // quantized_ste [M,512]
  float* out1 = out0 + (size_t)M * D;        // loss          [M,512]
  float* out2 = out1 + (size_t)M * D;        // nn_idx (as f32) [M]
  float* out3 = out2 + M;                    // codebook copy [K,512]

  char* ws = (char*)d_ws;
  size_t off = 0;
  u16* Bpan = (u16*)(ws + off); off += (size_t)K * D * 4;     // hi+lo interleaved
  float* c2 = (float*)(ws + off); off += (size_t)K * 4;
  const int nsub = K / 64;                                    // 32
  float2* part = (float2*)(ws + off); off += (size_t)M * nsub * 8;
  u16* Apan = (u16*)(ws + off);
  const size_t need_big = off + (size_t)M * D * 4;
  const bool big = (ws_size >= need_big);

  vq_prep<<<K, 128, 0, stream>>>(CB, Bpan, c2, out3);
  const int nmt = M / 256, nnt = K / 256;
  const int nwg = nmt * nnt;                                  // 512
  if (big) {
    vq_prep<<<M, 128, 0, stream>>>(X, Apan, nullptr, nullptr);
    vq_gemm<0><<<nwg, 512, 0, stream>>>(X, Apan, Bpan, c2, part, nmt);
  } else {
    vq_gemm<1><<<nwg, 512, 0, stream>>>(X, nullptr, Bpan, c2, part, nmt);
  }
  vq_final<<<M / 4, 256, 0, stream>>>(X, CB, part, out0, out1, out2, nsub);
}

// Round 3
// 149.016 us; speedup vs baseline: 1.0586x; 1.0170x over previous
//
#include <hip/hip_runtime.h>
#include <cfloat>

typedef unsigned short u16;
typedef u16   u16x4 __attribute__((ext_vector_type(4)));
typedef float f32x4 __attribute__((ext_vector_type(4)));
typedef _Float16 f16x8 __attribute__((ext_vector_type(8)));

#define GL2LDS(gp, lp) __builtin_amdgcn_global_load_lds(                      \
    (const __attribute__((address_space(1))) void*)(gp),                      \
    (__attribute__((address_space(3))) void*)(lp), 16, 0, 0)

static __device__ __forceinline__ void fence_barrier() {
  asm volatile("" ::: "memory");
  __builtin_amdgcn_s_barrier();
  asm volatile("" ::: "memory");
}

__device__ __forceinline__ void f32_to_f16pair(float f, u16& hi, u16& lo) {
  _Float16 h = (_Float16)f;               // RNE
  _Float16 l = (_Float16)(f - (float)h);  // residual (exact subtraction)
  hi = __builtin_bit_cast(u16, h);
  lo = __builtin_bit_cast(u16, l);
}

// Pretile a [R,512] fp32 matrix into f16 hi/lo panels.
// Panel unit: (tile of 256 rows, K-step s of 32 cols) = 32768 bytes.
// Row layout inside a unit: 128 B = [hi: 32 f16 | lo: 32 f16], byte offset
// XOR-swizzled with ((r&7)<<4) — stored as the exact LDS image so
// global_load_lds can copy units linearly (swizzle both-sides, rule #21).
__global__ __launch_bounds__(128) void vq_prep(
    const float* __restrict__ src, u16* __restrict__ pan,
    float* __restrict__ sq, float* __restrict__ copy_out) {
  __shared__ float red[2];
  const int row_g = blockIdx.x;
  const int t = threadIdx.x;             // 0..127, 4 floats each
  float4 v = reinterpret_cast<const float4*>(src + (size_t)row_g * 512)[t];
  if (copy_out)
    reinterpret_cast<float4*>(copy_out + (size_t)row_g * 512)[t] = v;
  u16 hi[4], lo[4];
  float f[4] = {v.x, v.y, v.z, v.w};
  #pragma unroll
  for (int i = 0; i < 4; ++i) f32_to_f16pair(f[i], hi[i], lo[i]);
  const int d = t * 4;
  const int tile = row_g >> 8, r = row_g & 255;
  const int s = d >> 5, c = d & 31;
  const size_t pbase = ((size_t)tile * 16 + s) * 32768;
  const unsigned swz = ((unsigned)(r & 7)) << 4;
  const unsigned bh = ((unsigned)(r * 128 + c * 2)) ^ swz;
  const unsigned bl = ((unsigned)(r * 128 + 64 + c * 2)) ^ swz;
  u16x4 th = {hi[0], hi[1], hi[2], hi[3]};
  u16x4 tl = {lo[0], lo[1], lo[2], lo[3]};
  *reinterpret_cast<u16x4*>((char*)pan + pbase + bh) = th;
  *reinterpret_cast<u16x4*>((char*)pan + pbase + bl) = tl;
  if (sq) {
    float ssum = v.x*v.x + v.y*v.y + v.z*v.z + v.w*v.w;
    #pragma unroll
    for (int m = 1; m < 64; m <<= 1) ssum += __shfl_xor(ssum, m);
    if ((t & 63) == 0) red[t >> 6] = ssum;
    __syncthreads();
    if (t == 0) sq[row_g] = red[0] + red[1];
  }
}

// Distance GEMM + per-tile argmin. Tile 256x256, BK=32, 8 waves (2x4),
// per-wave output 128x64. mfma_f32_16x16x32_f16, hi/lo split (3 MFMAs).
// 8-phase-style schedule: 4 phases per K-step (one acc-row-pair each),
// B staged in phase 0, A in phase 1, raw s_barrier pairs per phase,
// setprio(1) around MFMA clusters, vmcnt(0) only at the K-step boundary.
// score = c2[col] - 2*dot (x2 row-constant, dropped for argmin).
template <int INLINE_A>
__global__ __launch_bounds__(512, 2) void vq_gemm(
    const float* __restrict__ X,
    const u16* __restrict__ Apan, const u16* __restrict__ Bpan,
    const float* __restrict__ c2,
    float2* __restrict__ part, int nnt) {
  __shared__ u16 sA[2][16384], sB[2][16384];   // 2 x 32 KiB each
  const int tid = threadIdx.x;
  const int lane = tid & 63, wid = tid >> 6;   // 8 waves
  const int wm = wid >> 2, wn = wid & 3;       // 2 x 4
  // bijective XCD swizzle (nwg % 8 == 0); each XCD owns a contiguous
  // mtile band so A-panel reads stay in its private L2.
  const int nwg = gridDim.x;
  const int bid = blockIdx.x;
  const int swb = (bid & 7) * (nwg >> 3) + (bid >> 3);
  const int mtile = swb / nnt, ntile = swb % nnt;
  const int lrow = lane & 15, kgrp = lane >> 4;
  f32x4 acc[8][4] = {};

  auto stageB = [&](int s, int buf) {
    const char* gb = (const char*)Bpan + ((size_t)ntile * 16 + s) * 32768;
    #pragma unroll
    for (int ch = 0; ch < 4; ++ch) {
      const int off = (wid * 4 + ch) * 1024;
      GL2LDS(gb + off + lane * 16, (char*)sB[buf] + off);
    }
  };
  auto stageA = [&](int s, int buf) {
    const char* ga = (const char*)Apan + ((size_t)mtile * 16 + s) * 32768;
    #pragma unroll
    for (int ch = 0; ch < 4; ++ch) {
      const int off = (wid * 4 + ch) * 1024;
      GL2LDS(ga + off + lane * 16, (char*)sA[buf] + off);
    }
  };
  auto inlineA = [&](int s, int buf) {
    const float* ga = X + ((size_t)mtile * 256) * 512 + s * 32;
    #pragma unroll
    for (int p = 0; p < 4; ++p) {
      const int cch = tid + p * 512;           // 2048 float4 chunks
      const int r = cch >> 3, c0 = (cch & 7) * 4;
      float4 v = *reinterpret_cast<const float4*>(ga + (size_t)r * 512 + c0);
      u16 hi[4], lo[4];
      float f[4] = {v.x, v.y, v.z, v.w};
      #pragma unroll
      for (int i2 = 0; i2 < 4; ++i2) f32_to_f16pair(f[i2], hi[i2], lo[i2]);
      const unsigned swz = ((unsigned)(r & 7)) << 4;
      const unsigned bh = ((unsigned)(r * 128 + c0 * 2)) ^ swz;
      const unsigned bl = ((unsigned)(r * 128 + 64 + c0 * 2)) ^ swz;
      u16x4 th = {hi[0], hi[1], hi[2], hi[3]};
      u16x4 tl = {lo[0], lo[1], lo[2], lo[3]};
      *reinterpret_cast<u16x4*>((char*)sA[buf] + bh) = th;
      *reinterpret_cast<u16x4*>((char*)sA[buf] + bl) = tl;
    }
  };

  // ---- prologue: stage step 0 fully, drain, barrier
  stageB(0, 0);
  if constexpr (INLINE_A) inlineA(0, 0); else stageA(0, 0);
  asm volatile("s_waitcnt vmcnt(0) lgkmcnt(0)" ::: "memory");
  __builtin_amdgcn_s_barrier();
  asm volatile("" ::: "memory");

  int cur = 0;
  f16x8 bhi[4], blo[4];
  for (int s = 0; s < 16; ++s) {
    const int nxt = cur ^ 1;
    #pragma unroll
    for (int q = 0; q < 4; ++q) {
      // ---- ds-read front for this phase's quadrant
      if (q == 0) {
        #pragma unroll
        for (int j = 0; j < 4; ++j) {
          const int br = wn * 64 + j * 16 + lrow;
          const unsigned swz = ((unsigned)(br & 7)) << 4;
          const unsigned b0 = (unsigned)(br * 128 + kgrp * 16);
          bhi[j] = *reinterpret_cast<const f16x8*>((const char*)sB[cur] + (b0 ^ swz));
          blo[j] = *reinterpret_cast<const f16x8*>((const char*)sB[cur] + ((b0 + 64) ^ swz));
        }
      }
      f16x8 ahi[2], alo[2];
      #pragma unroll
      for (int t = 0; t < 2; ++t) {
        const int i = q * 2 + t;
        const int ar = wm * 128 + i * 16 + lrow;
        const unsigned swz = ((unsigned)(ar & 7)) << 4;
        const unsigned a0 = (unsigned)(ar * 128 + kgrp * 16);
        ahi[t] = *reinterpret_cast<const f16x8*>((const char*)sA[cur] + (a0 ^ swz));
        alo[t] = *reinterpret_cast<const f16x8*>((const char*)sA[cur] + ((a0 + 64) ^ swz));
      }
      // ---- issue next-step staging (B in phase 0, A in phase 1)
      if (s + 1 < 16) {
        if (q == 0) stageB(s + 1, nxt);
        if (q == 1) { if constexpr (INLINE_A) inlineA(s + 1, nxt); else stageA(s + 1, nxt); }
      }
      fence_barrier();
      asm volatile("s_waitcnt lgkmcnt(0)" ::: "memory");
      __builtin_amdgcn_sched_barrier(0);
      __builtin_amdgcn_s_setprio(1);
      #pragma unroll
      for (int t = 0; t < 2; ++t) {
        const int i = q * 2 + t;
        #pragma unroll
        for (int j = 0; j < 4; ++j) {
          acc[i][j] = __builtin_amdgcn_mfma_f32_16x16x32_f16(ahi[t], bhi[j], acc[i][j], 0, 0, 0);
          acc[i][j] = __builtin_amdgcn_mfma_f32_16x16x32_f16(ahi[t], blo[j], acc[i][j], 0, 0, 0);
          acc[i][j] = __builtin_amdgcn_mfma_f32_16x16x32_f16(alo[t], bhi[j], acc[i][j], 0, 0, 0);
        }
      }
      __builtin_amdgcn_s_setprio(0);
      if (q == 3)  // K-step boundary: own prefetch must be in LDS past barrier
        asm volatile("s_waitcnt vmcnt(0) lgkmcnt(0)" ::: "memory");
      fence_barrier();
    }
    cur ^= 1;
  }

  // ---- epilogue: per-row argmin over this wave's 64 cols, tie-break low idx
  float c2v[4];
  #pragma unroll
  for (int j = 0; j < 4; ++j) c2v[j] = c2[ntile * 256 + wn * 64 + j * 16 + lrow];
  #pragma unroll
  for (int i = 0; i < 8; ++i) {
    #pragma unroll
    for (int jj = 0; jj < 4; ++jj) {
      float v = FLT_MAX; int idx = 0x7fffffff;
      #pragma unroll
      for (int j = 0; j < 4; ++j) {
        const float sc = c2v[j] - 2.0f * acc[i][j][jj];
        const int col = ntile * 256 + wn * 64 + j * 16 + lrow;
        if (sc < v || (sc == v && col < idx)) { v = sc; idx = col; }
      }
      #pragma unroll
      for (int m = 1; m < 16; m <<= 1) {
        const float ov = __shfl_xor(v, m);
        const int oi = __shfl_xor(idx, m);
        if (ov < v || (ov == v && oi < idx)) { v = ov; idx = oi; }
      }
      if (lrow == 0) {
        const int row = mtile * 256 + wm * 128 + i * 16 + kgrp * 4 + jj;
        part[(size_t)row * 32 + (ntile * 4 + wn)] =
            make_float2(v, __int_as_float(idx));
      }
    }
  }
}

// Final: reduce 32 partials per row, gather codebook row, write outputs.
__global__ __launch_bounds__(256) void vq_final(
    const float* __restrict__ X, const float* __restrict__ CB,
    const float2* __restrict__ part,
    float* __restrict__ out0, float* __restrict__ out1, float* __restrict__ out2,
    int nsub) {
  const int row = blockIdx.x * 4 + (threadIdx.x >> 6);
  const int l = threadIdx.x & 63;
  float v = FLT_MAX; int idx = 0x7fffffff;
  for (int i = l; i < nsub; i += 64) {
    const float2 p = part[(size_t)row * nsub + i];
    const int pi = __float_as_int(p.y);
    if (p.x < v || (p.x == v && pi < idx)) { v = p.x; idx = pi; }
  }
  #pragma unroll
  for (int m = 1; m < 64; m <<= 1) {
    const float ov = __shfl_xor(v, m);
    const int oi = __shfl_xor(idx, m);
    if (ov < v || (ov == v && oi < idx)) { v = ov; idx = oi; }
  }
  const float4* xr = reinterpret_cast<const float4*>(X + (size_t)row * 512);
  const float4* cr = reinterpret_cast<const float4*>(CB + (size_t)idx * 512);
  float4* q  = reinterpret_cast<float4*>(out0 + (size_t)row * 512);
  float4* ls = reinterpret_cast<float4*>(out1 + (size_t)row * 512);
  #pragma unroll
  for (int p = 0; p < 2; ++p) {
    const int e = l + 64 * p;
    const float4 xv = xr[e], cv = cr[e];
    float4 d4, qv, lv;
    d4.x = cv.x - xv.x; d4.y = cv.y - xv.y; d4.z = cv.z - xv.z; d4.w = cv.w - xv.w;
    qv.x = xv.x + d4.x; qv.y = xv.y + d4.y; qv.z = xv.z + d4.z; qv.w = xv.w + d4.w;
    lv.x = d4.x * d4.x; lv.y = d4.y * d4.y; lv.z = d4.z * d4.z; lv.w = d4.w * d4.w;
    q[e] = qv; ls[e] = lv;
  }
  if (l == 0) out2[row] = (float)idx;
}

extern "C" void kernel_launch(void* const* d_in, const int* in_sizes, int n_in,
                              void* d_out, int out_size, void* d_ws, size_t ws_size,
                              hipStream_t stream) {
  const float* X  = (const float*)d_in[0];   // [M,512] fp32
  const float* CB = (const float*)d_in[1];   // [K,512] fp32
  const int D = 512;
  const int M = in_sizes[0] / D;             // 16384
  const int K = in_sizes[1] / D;             // 2048
  float* out0 = (float*)d_out;               // quantized_ste [M,512]
  float* out1 = out0 + (size_t)M * D;        // loss          [M,512]
  float* out2 = out1 + (size_t)M * D;        // nn_idx (as f32) [M]
  float* out3 = out2 + M;                    // codebook copy [K,512]

  char* ws = (char*)d_ws;
  size_t off = 0;
  u16* Bpan = (u16*)(ws + off); off += (size_t)K * D * 4;     // hi+lo interleaved
  float* c2 = (float*)(ws + off); off += (size_t)K * 4;
  const int nsub = K / 64;                                    // 32
  float2* part = (float2*)(ws + off); off += (size_t)M * nsub * 8;
  u16* Apan = (u16*)(ws + off);
  const size_t need_big = off + (size_t)M * D * 4;
  const bool big = (ws_size >= need_big);

  vq_prep<<<K, 128, 0, stream>>>(CB, Bpan, c2, out3);
  const int nmt = M / 256, nnt = K / 256;
  const int nwg = nmt * nnt;                                  // 512
  if (big) {
    vq_prep<<<M, 128, 0, stream>>>(X, Apan, nullptr, nullptr);
    vq_gemm<0><<<nwg, 512, 0, stream>>>(X, Apan, Bpan, c2, part, nnt);
  } else {
    vq_gemm<1><<<nwg, 512, 0, stream>>>(X, nullptr, Bpan, c2, part, nnt);
  }
  vq_final<<<M / 4, 256, 0, stream>>>(X, CB, part, out0, out1, out2, nsub);
}